// Round 1
// baseline (314.458 us; speedup 1.0000x reference)
//
#include <hip/hip_runtime.h>
#include <hip/hip_bf16.h>

// Problem constants (from reference setup_inputs)
#define BB 2
#define NN 16384          // points per batch (2^14)
#define NP 4096           // query points per batch
#define CC 64             // feature channels
#define SS 32             // nsample
#define NCH (3 + CC)      // 67 output channels

#define NSUB 16           // point-range subsets per query group
#define SUBN (NN / NSUB)  // 1024 points per subset

// ---------------------------------------------------------------------------
// Kernel 1: pack xyz (B,N,3) -> float4 (B,N,4) for 16B scalar loads
// ---------------------------------------------------------------------------
__global__ void __launch_bounds__(256) pack_xyz_kernel(
    const float* __restrict__ xyz, float4* __restrict__ xyz4)
{
    int i = blockIdx.x * 256 + threadIdx.x;   // 0 .. B*N-1
    if (i < BB * NN) {
        float4 v;
        v.x = xyz[3 * i + 0];
        v.y = xyz[3 * i + 1];
        v.z = xyz[3 * i + 2];
        v.w = 0.0f;
        xyz4[i] = v;
    }
}

// ---------------------------------------------------------------------------
// Kernel 2: transpose features (B,C,N) -> (B,N,C) so per-sample channel
// gathers in the group kernel are 256B contiguous.
// ---------------------------------------------------------------------------
__global__ void __launch_bounds__(256) transpose_feat_kernel(
    const float* __restrict__ f, float* __restrict__ ft)
{
    __shared__ float tile[64 * 65];
    const int b  = blockIdx.y;
    const int n0 = blockIdx.x * 64;
    const int t  = threadIdx.x;
    const int tn  = t & 63;   // 0..63
    const int tc4 = t >> 6;   // 0..3
#pragma unroll
    for (int r = 0; r < 16; ++r) {
        int c = r * 4 + tc4;
        tile[c * 65 + tn] = f[((b * CC + c) << 14) + n0 + tn];  // coalesced read
    }
    __syncthreads();
#pragma unroll
    for (int r = 0; r < 16; ++r) {
        int nl = r * 4 + tc4;
        // write ft[b][n0+nl][tn] — coalesced across lanes; LDS read 2-way (free)
        ft[((b << 14) + n0 + nl) * CC + tn] = tile[tn * 65 + nl];
    }
}

// ---------------------------------------------------------------------------
// Kernel 3: ball query partials. lane = query (64 queries per group),
// blockIdx.y = point-subset. Per-lane ordered selection of first <=32 valid
// indices within the subset (cap 32 per subset is lossless for final first-32).
// ---------------------------------------------------------------------------
__global__ void __launch_bounds__(64) query_kernel(
    const float4* __restrict__ xyz4, const float* __restrict__ new_xyz,
    int* __restrict__ part, int* __restrict__ cntp)
{
#pragma clang fp contract(off)
    const int g    = blockIdx.x;        // 0..127 query group
    const int sub  = blockIdx.y;        // 0..NSUB-1
    const int lane = threadIdx.x;       // 0..63
    const int q    = g * 64 + lane;     // global query id, same batch per group
    const int b    = q >> 12;           // 4096 queries per batch

    // radius constants computed exactly like the reference (double mul -> f32)
    const float RMIN2 = (float)(0.4 * 0.4);
    const float RMAX2 = (float)(0.8 * 0.8);

    const float qx = new_xyz[q * 3 + 0];
    const float qy = new_xyz[q * 3 + 1];
    const float qz = new_xyz[q * 3 + 2];

    const float4* __restrict__ pts = xyz4 + (b << 14) + sub * SUBN;
    int* __restrict__ mypart = part + (q * NSUB + sub) * SS;
    const int base = sub * SUBN;

    int cnt = 0;
#pragma unroll 4
    for (int j = 0; j < SUBN; ++j) {
        float4 pt = pts[j];                       // uniform addr -> s_load
        float dx = pt.x - qx;
        float dy = pt.y - qy;
        float dz = pt.z - qz;
        float dx2 = dx * dx;
        float dy2 = dy * dy;
        float dz2 = dz * dz;
        float d2 = (dx2 + dy2) + dz2;             // contract(off): mul+add order
        bool valid = (d2 >= RMIN2) && (d2 < RMAX2);
        if (valid && cnt < SS) {
            mypart[cnt] = base + j;
            cnt++;
        }
    }
    cntp[q * NSUB + sub] = cnt;
}

// ---------------------------------------------------------------------------
// Kernel 4: merge per-subset ordered partials -> final idx (B,P,32) with
// reference fill semantics (pad with first valid index; zeros if none).
// ---------------------------------------------------------------------------
__global__ void __launch_bounds__(256) merge_kernel(
    const int* __restrict__ part, const int* __restrict__ cntp,
    int* __restrict__ idxg)
{
    int q = blockIdx.x * 256 + threadIdx.x;   // 0..8191
    const int* __restrict__ p = part + q * NSUB * SS;
    const int* __restrict__ c = cntp + q * NSUB;
    int* __restrict__ o = idxg + q * SS;

    int total = 0;
    int first = 0;   // reference: idx stays 0 when cnt==0
    for (int sub = 0; sub < NSUB && total < SS; ++sub) {
        int cs = c[sub];
        for (int j = 0; j < cs; ++j) {
            if (total < SS) {
                int v = p[sub * SS + j];
                if (total == 0) first = v;
                o[total++] = v;
            }
        }
    }
    for (int s = total; s < SS; ++s) o[s] = first;
}

// ---------------------------------------------------------------------------
// Kernel 5: grouping. One wave per query point. Gather 64-channel rows of
// transposed features (256B coalesced), stage in LDS [32][65], write out
// s-contiguous (coalesced 128B segments). xyz diff channels handled directly.
// ---------------------------------------------------------------------------
__global__ void __launch_bounds__(256) group_kernel(
    const float4* __restrict__ xyz4, const float* __restrict__ new_xyz,
    const float* __restrict__ ft, const int* __restrict__ idxg,
    float* __restrict__ out)
{
    __shared__ float tile[4][SS * 65];
    const int w    = threadIdx.x >> 6;
    const int lane = threadIdx.x & 63;
    const int q    = blockIdx.x * 4 + w;   // 0..8191
    const int b    = q >> 12;
    const int p    = q & (NP - 1);
    const int s    = lane & 31;

    const int idxv = idxg[q * SS + s];     // both half-waves read same 128B

    // --- grouped_xyz channels 0..2 ---
    float4 pt = xyz4[(b << 14) + idxv];
    float q0 = new_xyz[q * 3 + 0];
    float q1 = new_xyz[q * 3 + 1];
    float q2 = new_xyz[q * 3 + 2];
    if (lane < 32) {
        out[((b * NCH + 0) * NP + p) * SS + s] = pt.x - q0;
        out[((b * NCH + 1) * NP + p) * SS + s] = pt.y - q1;
        out[((b * NCH + 2) * NP + p) * SS + s] = pt.z - q2;
    }

    // --- feature channels: gather rows of ft into LDS ---
    float* tl = tile[w];
#pragma unroll 8
    for (int s2 = 0; s2 < SS; ++s2) {
        int n = __shfl(idxv, s2);                       // sample s2's index
        tl[s2 * 65 + lane] = ft[(((b << 14) + n) << 6) + lane];  // 256B coalesced
    }
    __syncthreads();
    // --- write out[b][3+c][p][s]: lanes cover (c, c+1) x s∈0..31 ---
    const int chalf = lane >> 5;
#pragma unroll 8
    for (int cp = 0; cp < 32; ++cp) {
        int cch = cp * 2 + chalf;
        out[((b * NCH + 3 + cch) * NP + p) * SS + s] = tl[s * 65 + cch];
    }
}

// ---------------------------------------------------------------------------
extern "C" void kernel_launch(void* const* d_in, const int* in_sizes, int n_in,
                              void* d_out, int out_size, void* d_ws, size_t ws_size,
                              hipStream_t stream)
{
    const float* xyz      = (const float*)d_in[0];   // (B,N,3)
    const float* new_xyz  = (const float*)d_in[1];   // (B,NP,3)
    const float* features = (const float*)d_in[2];   // (B,C,N)
    float* out = (float*)d_out;                      // (B,67,NP,32)

    // workspace layout (bytes): total ~26 MB
    char* ws = (char*)d_ws;
    float4* xyz4 = (float4*)(ws);                                  // 512 KB
    float*  ft   = (float*)(ws + 524288);                          // 8 MB
    int*    part = (int*)(ws + 524288 + 8388608);                  // 16 MB
    int*    cntp = (int*)(ws + 524288 + 8388608 + 16777216);       // 512 KB
    int*    idxg = (int*)(ws + 524288 + 8388608 + 16777216 + 524288); // 1 MB

    hipLaunchKernelGGL(pack_xyz_kernel, dim3((BB * NN) / 256), dim3(256), 0, stream,
                       xyz, xyz4);
    hipLaunchKernelGGL(transpose_feat_kernel, dim3(NN / 64, BB), dim3(256), 0, stream,
                       features, ft);
    hipLaunchKernelGGL(query_kernel, dim3(128, NSUB), dim3(64), 0, stream,
                       xyz4, new_xyz, part, cntp);
    hipLaunchKernelGGL(merge_kernel, dim3((BB * NP) / 256), dim3(256), 0, stream,
                       part, cntp, idxg);
    hipLaunchKernelGGL(group_kernel, dim3((BB * NP) / 4), dim3(256), 0, stream,
                       xyz4, new_xyz, ft, idxg, out);
}

// Round 4
// 164.485 us; speedup vs baseline: 1.9118x; 1.9118x over previous
//
#include <hip/hip_runtime.h>
#include <hip/hip_bf16.h>

// Problem constants (from reference setup_inputs)
#define BB 2
#define NN 16384          // points per batch (2^14)
#define NP 4096           // query points per batch
#define CC 64             // feature channels
#define SS 32             // nsample
#define NCH (3 + CC)      // 67 output channels

#define NSUB 32           // point-range subsets
#define SUBN (NN / NSUB)  // 512 points per subset

// ---------------------------------------------------------------------------
// Kernel 1: pack xyz (B,N,3) -> float4 (B,N,4) for 16B loads
// ---------------------------------------------------------------------------
__global__ void __launch_bounds__(256) pack_xyz_kernel(
    const float* __restrict__ xyz, float4* __restrict__ xyz4)
{
    int i = blockIdx.x * 256 + threadIdx.x;   // 0 .. B*N-1
    if (i < BB * NN) {
        float4 v;
        v.x = xyz[3 * i + 0];
        v.y = xyz[3 * i + 1];
        v.z = xyz[3 * i + 2];
        v.w = 0.0f;
        xyz4[i] = v;
    }
}

// ---------------------------------------------------------------------------
// Kernel 2: transpose features (B,C,N) -> (B,N,C) so per-sample channel
// gathers in the group kernel are 256B contiguous.
// ---------------------------------------------------------------------------
__global__ void __launch_bounds__(256) transpose_feat_kernel(
    const float* __restrict__ f, float* __restrict__ ft)
{
    __shared__ float tile[64 * 65];
    const int b  = blockIdx.y;
    const int n0 = blockIdx.x * 64;
    const int t  = threadIdx.x;
    const int tn  = t & 63;   // 0..63
    const int tc4 = t >> 6;   // 0..3
#pragma unroll
    for (int r = 0; r < 16; ++r) {
        int c = r * 4 + tc4;
        tile[c * 65 + tn] = f[((b * CC + c) << 14) + n0 + tn];  // coalesced read
    }
    __syncthreads();
#pragma unroll
    for (int r = 0; r < 16; ++r) {
        int nl = r * 4 + tc4;
        ft[((b << 14) + n0 + nl) * CC + tn] = tile[tn * 65 + nl];
    }
}

// ---------------------------------------------------------------------------
// Kernel 3: ball query partials. 256 threads = 256 queries per block;
// blockIdx.y = point-subset. Subset staged in LDS once; inner loop reads
// LDS with wave-uniform address (broadcast, conflict-free).
// Per-subset cap of 32 is lossless for the final first-32 selection.
// ---------------------------------------------------------------------------
__global__ void __launch_bounds__(256) query_kernel(
    const float4* __restrict__ xyz4, const float* __restrict__ new_xyz,
    unsigned short* __restrict__ part, unsigned char* __restrict__ cntp)
{
#pragma clang fp contract(off)
    __shared__ float4 pts_s[SUBN];          // 8 KB
    const int t   = threadIdx.x;            // 0..255
    const int sub = blockIdx.y;             // 0..NSUB-1
    const int q   = blockIdx.x * 256 + t;   // 0..8191 (block stays in one batch)
    const int b   = q >> 12;                // 4096 queries per batch

    const float RMIN2 = (float)(0.4 * 0.4);
    const float RMAX2 = (float)(0.8 * 0.8);

    // cooperative stage: 512 float4 = 8 KB, coalesced
    const float4* __restrict__ pts = xyz4 + (b << 14) + sub * SUBN;
#pragma unroll
    for (int i = 0; i < SUBN / 256; ++i)
        pts_s[i * 256 + t] = pts[i * 256 + t];
    __syncthreads();

    const float qx = new_xyz[q * 3 + 0];
    const float qy = new_xyz[q * 3 + 1];
    const float qz = new_xyz[q * 3 + 2];

    unsigned short* __restrict__ mypart = part + (q * NSUB + sub) * SS;
    const int base = sub * SUBN;

    int cnt = 0;
#pragma unroll 8
    for (int j = 0; j < SUBN; ++j) {
        float4 pt = pts_s[j];                     // uniform addr -> broadcast
        float dx = pt.x - qx;
        float dy = pt.y - qy;
        float dz = pt.z - qz;
        float dx2 = dx * dx;
        float dy2 = dy * dy;
        float dz2 = dz * dz;
        float d2 = (dx2 + dy2) + dz2;             // contract(off): match JAX order
        bool valid = (d2 >= RMIN2) && (d2 < RMAX2);
        if (valid && cnt < SS) {                  // rare -> execz-skipped
            mypart[cnt] = (unsigned short)(base + j);
            cnt++;
        }
    }
    cntp[q * NSUB + sub] = (unsigned char)cnt;
}

// ---------------------------------------------------------------------------
// Kernel 4: merge per-subset ordered partials -> final idx (B,P,32).
// One wave per query: lane = subset. Prefix-sum counts via shfl, parallel
// scatter copy, fill tail slots with first valid index (0 if none).
// ---------------------------------------------------------------------------
__global__ void __launch_bounds__(256) merge_kernel(
    const unsigned short* __restrict__ part, const unsigned char* __restrict__ cntp,
    int* __restrict__ idxg)
{
    const int lane = threadIdx.x & 63;
    const int w    = threadIdx.x >> 6;
    const int q    = blockIdx.x * 4 + w;    // 0..8191

    int c = (lane < NSUB) ? (int)cntp[q * NSUB + lane] : 0;

    // inclusive prefix sum over 64 lanes
    int off = c;
#pragma unroll
    for (int d = 1; d < 64; d <<= 1) {
        int v = __shfl_up(off, d);
        if (lane >= d) off += v;
    }
    int total = __shfl(off, 63);
    if (total > SS) total = SS;
    off -= c;                               // exclusive prefix = output offset

    // first valid index across the whole query (0 if none)
    const unsigned short* __restrict__ p = part + (q * NSUB + lane) * SS;
    int firstval = (c > 0) ? (int)p[0] : 0;
    unsigned long long m = __ballot(c > 0);
    int first = 0;
    if (m) {
        int fl = __ffsll((unsigned long long)m) - 1;
        first = __shfl(firstval, fl);
    }

    int* __restrict__ o = idxg + q * SS;
    // parallel ordered copy (short, divergent tails are rare)
    for (int j = 0; j < c; ++j) {
        int s = off + j;
        if (s < SS) o[s] = (int)p[j];
    }
    // fill tail slots [total, 32) with first
    if (lane < SS && lane >= total) o[lane] = first;
}

// ---------------------------------------------------------------------------
// Kernel 5: grouping. One wave per query point. Gather 64-channel rows of
// transposed features (256B coalesced), stage in LDS [32][65], write out
// s-contiguous. xyz diff channels handled directly.
// ---------------------------------------------------------------------------
__global__ void __launch_bounds__(256) group_kernel(
    const float4* __restrict__ xyz4, const float* __restrict__ new_xyz,
    const float* __restrict__ ft, const int* __restrict__ idxg,
    float* __restrict__ out)
{
    __shared__ float tile[4][SS * 65];
    const int w    = threadIdx.x >> 6;
    const int lane = threadIdx.x & 63;
    const int q    = blockIdx.x * 4 + w;   // 0..8191
    const int b    = q >> 12;
    const int p    = q & (NP - 1);
    const int s    = lane & 31;

    const int idxv = idxg[q * SS + s];     // both half-waves read same 128B

    // --- grouped_xyz channels 0..2 ---
    float4 pt = xyz4[(b << 14) + idxv];
    float q0 = new_xyz[q * 3 + 0];
    float q1 = new_xyz[q * 3 + 1];
    float q2 = new_xyz[q * 3 + 2];
    if (lane < 32) {
        out[((b * NCH + 0) * NP + p) * SS + s] = pt.x - q0;
        out[((b * NCH + 1) * NP + p) * SS + s] = pt.y - q1;
        out[((b * NCH + 2) * NP + p) * SS + s] = pt.z - q2;
    }

    // --- feature channels: gather rows of ft into LDS ---
    float* tl = tile[w];
#pragma unroll 8
    for (int s2 = 0; s2 < SS; ++s2) {
        int n = __shfl(idxv, s2);                       // sample s2's index
        tl[s2 * 65 + lane] = ft[(((b << 14) + n) << 6) + lane];  // 256B coalesced
    }
    __syncthreads();
    // --- write out[b][3+c][p][s]: lanes cover (c, c+1) x s in 0..31 ---
    const int chalf = lane >> 5;
#pragma unroll 8
    for (int cp = 0; cp < 32; ++cp) {
        int cch = cp * 2 + chalf;
        out[((b * NCH + 3 + cch) * NP + p) * SS + s] = tl[s * 65 + cch];
    }
}

// ---------------------------------------------------------------------------
extern "C" void kernel_launch(void* const* d_in, const int* in_sizes, int n_in,
                              void* d_out, int out_size, void* d_ws, size_t ws_size,
                              hipStream_t stream)
{
    const float* xyz      = (const float*)d_in[0];   // (B,N,3)
    const float* new_xyz  = (const float*)d_in[1];   // (B,NP,3)
    const float* features = (const float*)d_in[2];   // (B,C,N)
    float* out = (float*)d_out;                      // (B,67,NP,32)

    // workspace layout (bytes), total ~25.8 MB
    char* ws = (char*)d_ws;
    float4*         xyz4 = (float4*)(ws);                      // 524288 B
    float*          ft   = (float*)(ws + 524288);              // 8388608 B
    unsigned short* part = (unsigned short*)(ws + 8912896);    // 16777216 B
    unsigned char*  cntp = (unsigned char*)(ws + 25690112);    // 262144 B
    int*            idxg = (int*)(ws + 25952256);              // 1048576 B

    hipLaunchKernelGGL(pack_xyz_kernel, dim3((BB * NN) / 256), dim3(256), 0, stream,
                       xyz, xyz4);
    hipLaunchKernelGGL(transpose_feat_kernel, dim3(NN / 64, BB), dim3(256), 0, stream,
                       features, ft);
    hipLaunchKernelGGL(query_kernel, dim3((BB * NP) / 256, NSUB), dim3(256), 0, stream,
                       xyz4, new_xyz, part, cntp);
    hipLaunchKernelGGL(merge_kernel, dim3((BB * NP) / 4), dim3(256), 0, stream,
                       part, cntp, idxg);
    hipLaunchKernelGGL(group_kernel, dim3((BB * NP) / 4), dim3(256), 0, stream,
                       xyz4, new_xyz, ft, idxg, out);
}

// Round 6
// 157.966 us; speedup vs baseline: 1.9907x; 1.0413x over previous
//
#include <hip/hip_runtime.h>
#include <hip/hip_bf16.h>

// Problem constants (from reference setup_inputs)
#define BB 2
#define NN 16384          // points per batch (2^14)
#define NP 4096           // query points per batch
#define CC 64             // feature channels
#define SS 32             // nsample
#define NCH (3 + CC)      // 67 output channels

#define NSUB 32           // point-range subsets
#define SUBN (NN / NSUB)  // 512 points per subset

// ---------------------------------------------------------------------------
// Kernel 1: pack xyz (B,N,3) -> float4 (B,N,4) for 16B loads
// ---------------------------------------------------------------------------
__global__ void __launch_bounds__(256) pack_xyz_kernel(
    const float* __restrict__ xyz, float4* __restrict__ xyz4)
{
    int i = blockIdx.x * 256 + threadIdx.x;   // 0 .. B*N-1
    if (i < BB * NN) {
        float4 v;
        v.x = xyz[3 * i + 0];
        v.y = xyz[3 * i + 1];
        v.z = xyz[3 * i + 2];
        v.w = 0.0f;
        xyz4[i] = v;
    }
}

// ---------------------------------------------------------------------------
// Kernel 2: transpose features (B,C,N) -> (B,N,C) so per-sample channel
// gathers in the group kernel are 256B contiguous.
// ---------------------------------------------------------------------------
__global__ void __launch_bounds__(256) transpose_feat_kernel(
    const float* __restrict__ f, float* __restrict__ ft)
{
    __shared__ float tile[64 * 65];
    const int b  = blockIdx.y;
    const int n0 = blockIdx.x * 64;
    const int t  = threadIdx.x;
    const int tn  = t & 63;   // 0..63
    const int tc4 = t >> 6;   // 0..3
#pragma unroll
    for (int r = 0; r < 16; ++r) {
        int c = r * 4 + tc4;
        tile[c * 65 + tn] = f[((b * CC + c) << 14) + n0 + tn];  // coalesced read
    }
    __syncthreads();
#pragma unroll
    for (int r = 0; r < 16; ++r) {
        int nl = r * 4 + tc4;
        ft[((b << 14) + n0 + nl) * CC + tn] = tile[tn * 65 + nl];
    }
}

// ---------------------------------------------------------------------------
// Kernel 3: ball query partials. 256 threads = 256 queries per block;
// blockIdx.y = point-subset. Subset staged in LDS; inner loop register-blocks
// 8 points (no loop-carried deps in the hot path), builds a per-lane validity
// bitmask, then a rarely-taken branch extracts ordered indices via ffs.
// Range test: for d2 >= 0, (bits(d2)-bits(lo)) < (bits(hi)-bits(lo)) is exact.
// Per-subset cap of 32 is lossless for the final first-32 selection.
// ---------------------------------------------------------------------------
__global__ void __launch_bounds__(256) query_kernel(
    const float4* __restrict__ xyz4, const float* __restrict__ new_xyz,
    unsigned short* __restrict__ part, unsigned char* __restrict__ cntp)
{
#pragma clang fp contract(off)
    __shared__ float4 pts_s[SUBN];          // 8 KB
    const int t   = threadIdx.x;            // 0..255
    const int sub = blockIdx.y;             // 0..NSUB-1
    const int q   = blockIdx.x * 256 + t;   // 0..8191 (block stays in one batch)
    const int b   = q >> 12;                // 4096 queries per batch

    const float RMIN2 = (float)(0.4 * 0.4);
    const float RMAX2 = (float)(0.8 * 0.8);
    const unsigned ULO = __float_as_uint(RMIN2);
    const unsigned URNG = __float_as_uint(RMAX2) - ULO;

    // cooperative stage: 512 float4 = 8 KB, coalesced
    const float4* __restrict__ pts = xyz4 + (b << 14) + sub * SUBN;
#pragma unroll
    for (int i = 0; i < SUBN / 256; ++i)
        pts_s[i * 256 + t] = pts[i * 256 + t];
    __syncthreads();

    const float qx = new_xyz[q * 3 + 0];
    const float qy = new_xyz[q * 3 + 1];
    const float qz = new_xyz[q * 3 + 2];

    unsigned short* __restrict__ mypart = part + (q * NSUB + sub) * SS;
    const int base = sub * SUBN;

    int cnt = 0;
    for (int j0 = 0; j0 < SUBN; j0 += 8) {
        float4 P[8];
#pragma unroll
        for (int k = 0; k < 8; ++k) P[k] = pts_s[j0 + k];   // batched b128 reads
        unsigned m = 0;
#pragma unroll
        for (int k = 0; k < 8; ++k) {
            float dx = P[k].x - qx;
            float dy = P[k].y - qy;
            float dz = P[k].z - qz;
            float dx2 = dx * dx;
            float dy2 = dy * dy;
            float dz2 = dz * dz;
            float d2 = (dx2 + dy2) + dz2;         // contract(off): match JAX order
            unsigned ud = __float_as_uint(d2);
            bool valid = (ud - ULO) < URNG;       // exact [lo,hi) test, d2>=0
            m |= valid ? (1u << k) : 0u;
        }
        if (m) {                                  // rare: ~1.5% of lane-chunks
            do {
                int k = __ffs(m) - 1;
                m &= m - 1;
                if (cnt < SS) {
                    mypart[cnt] = (unsigned short)(base + j0 + k);
                    cnt++;
                }
            } while (m);
        }
    }
    cntp[q * NSUB + sub] = (unsigned char)cnt;
}

// ---------------------------------------------------------------------------
// Kernel 4: merge per-subset ordered partials -> final idx (B,P,32).
// One wave per query: lane = subset. Prefix-sum counts via shfl, parallel
// scatter copy, fill tail slots with first valid index (0 if none).
// ---------------------------------------------------------------------------
__global__ void __launch_bounds__(256) merge_kernel(
    const unsigned short* __restrict__ part, const unsigned char* __restrict__ cntp,
    int* __restrict__ idxg)
{
    const int lane = threadIdx.x & 63;
    const int w    = threadIdx.x >> 6;
    const int q    = blockIdx.x * 4 + w;    // 0..8191

    int c = (lane < NSUB) ? (int)cntp[q * NSUB + lane] : 0;

    // inclusive prefix sum over 64 lanes
    int off = c;
#pragma unroll
    for (int d = 1; d < 64; d <<= 1) {
        int v = __shfl_up(off, d);
        if (lane >= d) off += v;
    }
    int total = __shfl(off, 63);
    if (total > SS) total = SS;
    off -= c;                               // exclusive prefix = output offset

    // first valid index across the whole query (0 if none)
    const unsigned short* __restrict__ p = part + (q * NSUB + lane) * SS;
    int firstval = (c > 0) ? (int)p[0] : 0;
    unsigned long long m = __ballot(c > 0);
    int first = 0;
    if (m) {
        int fl = __ffsll((unsigned long long)m) - 1;
        first = __shfl(firstval, fl);
    }

    int* __restrict__ o = idxg + q * SS;
    // parallel ordered copy (short, divergent tails are rare)
    for (int j = 0; j < c; ++j) {
        int s = off + j;
        if (s < SS) o[s] = (int)p[j];
    }
    // fill tail slots [total, 32) with first
    if (lane < SS && lane >= total) o[lane] = first;
}

// ---------------------------------------------------------------------------
// Kernel 5: grouping. One wave per query point; per-wave LDS tile [16][66]
// (no __syncthreads — tiles are wave-private, LDS pipe is in-order per wave;
// fences via s_waitcnt + memory clobber). Two 16-sample passes: gather 256B
// ft rows coalesced, transpose through LDS, write s-contiguous 64B segments.
// 16.9 KB LDS/block -> 8 blocks/CU = 32 waves/CU.
// ---------------------------------------------------------------------------
__global__ void __launch_bounds__(256) group_kernel(
    const float4* __restrict__ xyz4, const float* __restrict__ new_xyz,
    const float* __restrict__ ft, const int* __restrict__ idxg,
    float* __restrict__ out)
{
    __shared__ float tile[4][16 * 66];      // 4224 B per wave
    const int w    = threadIdx.x >> 6;
    const int lane = threadIdx.x & 63;
    const int q    = blockIdx.x * 4 + w;   // 0..8191
    const int b    = q >> 12;
    const int p    = q & (NP - 1);
    const int s    = lane & 31;

    const int idxv = idxg[q * SS + s];     // both half-waves read same 128B

    // --- grouped_xyz channels 0..2 ---
    float4 pt = xyz4[(b << 14) + idxv];
    float q0 = new_xyz[q * 3 + 0];
    float q1 = new_xyz[q * 3 + 1];
    float q2 = new_xyz[q * 3 + 2];
    if (lane < 32) {
        out[((b * NCH + 0) * NP + p) * SS + s] = pt.x - q0;
        out[((b * NCH + 1) * NP + p) * SS + s] = pt.y - q1;
        out[((b * NCH + 2) * NP + p) * SS + s] = pt.z - q2;
    }

    // --- feature channels, two passes of 16 samples ---
    float* tl = tile[w];
    const float* __restrict__ ftb = ft + (b << 14) * CC;
    const int sl = lane & 15;              // s within pass
    const int cq = lane >> 4;              // channel quarter 0..3
#pragma unroll
    for (int h = 0; h < 2; ++h) {
        // gather 16 rows of 256B (coalesced; 2x128B lines each)
#pragma unroll
        for (int s2 = 0; s2 < 16; ++s2) {
            int n = __shfl(idxv, h * 16 + s2);
            tl[s2 * 66 + lane] = ftb[(n << 6) + lane];
        }
        asm volatile("s_waitcnt lgkmcnt(0)" ::: "memory");  // writes visible wave-wide
        // write out[b][3+ch][p][h*16+sl]; banks (2*sl+cq) -> <=2-way, free
#pragma unroll
        for (int cp = 0; cp < 16; ++cp) {
            int ch = cp * 4 + cq;
            out[((b * NCH + 3 + ch) * NP + p) * SS + h * 16 + sl] = tl[sl * 66 + ch];
        }
        asm volatile("s_waitcnt lgkmcnt(0)" ::: "memory");  // reads drained before reuse
    }
}

// ---------------------------------------------------------------------------
extern "C" void kernel_launch(void* const* d_in, const int* in_sizes, int n_in,
                              void* d_out, int out_size, void* d_ws, size_t ws_size,
                              hipStream_t stream)
{
    const float* xyz      = (const float*)d_in[0];   // (B,N,3)
    const float* new_xyz  = (const float*)d_in[1];   // (B,NP,3)
    const float* features = (const float*)d_in[2];   // (B,C,N)
    float* out = (float*)d_out;                      // (B,67,NP,32)

    // workspace layout (bytes), total ~25.8 MB
    char* ws = (char*)d_ws;
    float4*         xyz4 = (float4*)(ws);                      // 524288 B
    float*          ft   = (float*)(ws + 524288);              // 8388608 B
    unsigned short* part = (unsigned short*)(ws + 8912896);    // 16777216 B
    unsigned char*  cntp = (unsigned char*)(ws + 25690112);    // 262144 B
    int*            idxg = (int*)(ws + 25952256);              // 1048576 B

    hipLaunchKernelGGL(pack_xyz_kernel, dim3((BB * NN) / 256), dim3(256), 0, stream,
                       xyz, xyz4);
    hipLaunchKernelGGL(transpose_feat_kernel, dim3(NN / 64, BB), dim3(256), 0, stream,
                       features, ft);
    hipLaunchKernelGGL(query_kernel, dim3((BB * NP) / 256, NSUB), dim3(256), 0, stream,
                       xyz4, new_xyz, part, cntp);
    hipLaunchKernelGGL(merge_kernel, dim3((BB * NP) / 4), dim3(256), 0, stream,
                       part, cntp, idxg);
    hipLaunchKernelGGL(group_kernel, dim3((BB * NP) / 4), dim3(256), 0, stream,
                       xyz4, new_xyz, ft, idxg, out);
}

// Round 8
// 146.134 us; speedup vs baseline: 2.1518x; 1.0810x over previous
//
#include <hip/hip_runtime.h>
#include <hip/hip_bf16.h>

// Problem constants (from reference setup_inputs)
#define BB 2
#define NN 16384          // points per batch (2^14)
#define NP 4096           // query points per batch
#define CC 64             // feature channels
#define SS 32             // nsample
#define NCH (3 + CC)      // 67 output channels

#define NSUB 32           // point-range subsets
#define SUBN (NN / NSUB)  // 512 points per subset
#define QB 32             // queries per wave in query_kernel

// ---------------------------------------------------------------------------
// Kernel 1: pack xyz (B,N,3) -> float4 (B,N,4) for 16B loads
// ---------------------------------------------------------------------------
__global__ void __launch_bounds__(256) pack_xyz_kernel(
    const float* __restrict__ xyz, float4* __restrict__ xyz4)
{
    int i = blockIdx.x * 256 + threadIdx.x;   // 0 .. B*N-1
    if (i < BB * NN) {
        float4 v;
        v.x = xyz[3 * i + 0];
        v.y = xyz[3 * i + 1];
        v.z = xyz[3 * i + 2];
        v.w = 0.0f;
        xyz4[i] = v;
    }
}

// ---------------------------------------------------------------------------
// Kernel 2: transpose features (B,C,N) -> (B,N,C) so per-sample channel
// gathers in the group kernel are 256B contiguous.
// ---------------------------------------------------------------------------
__global__ void __launch_bounds__(256) transpose_feat_kernel(
    const float* __restrict__ f, float* __restrict__ ft)
{
    __shared__ float tile[64 * 65];
    const int b  = blockIdx.y;
    const int n0 = blockIdx.x * 64;
    const int t  = threadIdx.x;
    const int tn  = t & 63;   // 0..63
    const int tc4 = t >> 6;   // 0..3
#pragma unroll
    for (int r = 0; r < 16; ++r) {
        int c = r * 4 + tc4;
        tile[c * 65 + tn] = f[((b * CC + c) << 14) + n0 + tn];  // coalesced read
    }
    __syncthreads();
#pragma unroll
    for (int r = 0; r < 16; ++r) {
        int nl = r * 4 + tc4;
        ft[((b << 14) + n0 + nl) * CC + tn] = tile[tn * 65 + nl];
    }
}

// ---------------------------------------------------------------------------
// Kernel 3: ball query partials — lane = POINT, queries broadcast as scalars.
// Each wave holds its subset's 512 points in registers (8 float4 per lane)
// and iterates QB=32 queries. Validity -> __ballot; matched lanes self-assign
// ordered slots via popcount(mask & lanemask_lt). Chunk order (k asc) x lane
// order (asc) = ascending point index, so per-subset lists stay ordered.
// No LDS at all — removes the 2.1M ds_read_b128 stream that bound Round 6.
// Range test: for d2 >= 0, (bits(d2)-bits(lo)) < (bits(hi)-bits(lo)) is exact.
// ---------------------------------------------------------------------------
__global__ void __launch_bounds__(256) query_kernel(
    const float4* __restrict__ xyz4, const float* __restrict__ new_xyz,
    unsigned short* __restrict__ part, unsigned char* __restrict__ cntp)
{
#pragma clang fp contract(off)
    const int lane = threadIdx.x & 63;
    const int wid  = blockIdx.x * 4 + (threadIdx.x >> 6);  // 0..8191
    const int b    = wid >> 12;            // 4096 waves per batch
    const int r    = wid & 4095;
    const int sub  = r >> 7;               // 0..31
    const int qb   = r & 127;              // 0..127
    const int qbase = qb * QB;             // within-batch first query

    const float RMIN2 = (float)(0.4 * 0.4);
    const float RMAX2 = (float)(0.8 * 0.8);
    const unsigned ULO  = __float_as_uint(RMIN2);
    const unsigned URNG = __float_as_uint(RMAX2) - ULO;

    // load this wave's 512 points into registers: 8 chunks of 64 (coalesced)
    const float4* __restrict__ pb = xyz4 + (b << 14) + sub * SUBN;
    float4 P[8];
#pragma unroll
    for (int k = 0; k < 8; ++k) P[k] = pb[k * 64 + lane];

    const unsigned long long ltmask = (1ull << lane) - 1ull;
    int mycnt = 0;

    for (int j = 0; j < QB; ++j) {
        const int qg = b * NP + qbase + j;             // global query id
        // wave-uniform -> force scalar loads (s_load, scalar cache)
        const int qoff = __builtin_amdgcn_readfirstlane(qg * 3);
        const float qx = new_xyz[qoff + 0];
        const float qy = new_xyz[qoff + 1];
        const float qz = new_xyz[qoff + 2];

        unsigned short* __restrict__ mp = part + ((size_t)qg * NSUB + sub) * SS;
        int cnt = 0;
#pragma unroll
        for (int k = 0; k < 8; ++k) {
            float dx = P[k].x - qx;
            float dy = P[k].y - qy;
            float dz = P[k].z - qz;
            float dx2 = dx * dx;
            float dy2 = dy * dy;
            float dz2 = dz * dz;
            float d2 = (dx2 + dy2) + dz2;              // contract(off): JAX order
            bool valid = (__float_as_uint(d2) - ULO) < URNG;
            unsigned long long m = __ballot(valid);
            if (m) {                                   // wave-uniform, ~12% taken
                if (valid) {
                    int slot = cnt + (int)__popcll(m & ltmask);
                    if (slot < SS)
                        mp[slot] = (unsigned short)(sub * SUBN + k * 64 + lane);
                }
                cnt += (int)__popcll(m);
            }
        }
        if (cnt > SS) cnt = SS;
        mycnt = (lane == j) ? cnt : mycnt;             // collect for one store
    }
    if (lane < QB)
        cntp[(size_t)(b * NP + qbase + lane) * NSUB + sub] = (unsigned char)mycnt;
}

// ---------------------------------------------------------------------------
// Kernel 4: merge per-subset ordered partials -> final idx (B,P,32).
// One wave per query: lane = subset. Prefix-sum counts via shfl, parallel
// scatter copy, fill tail slots with first valid index (0 if none).
// ---------------------------------------------------------------------------
__global__ void __launch_bounds__(256) merge_kernel(
    const unsigned short* __restrict__ part, const unsigned char* __restrict__ cntp,
    int* __restrict__ idxg)
{
    const int lane = threadIdx.x & 63;
    const int w    = threadIdx.x >> 6;
    const int q    = blockIdx.x * 4 + w;    // 0..8191

    int c = (lane < NSUB) ? (int)cntp[q * NSUB + lane] : 0;

    // inclusive prefix sum over 64 lanes
    int off = c;
#pragma unroll
    for (int d = 1; d < 64; d <<= 1) {
        int v = __shfl_up(off, d);
        if (lane >= d) off += v;
    }
    int total = __shfl(off, 63);
    if (total > SS) total = SS;
    off -= c;                               // exclusive prefix = output offset

    // first valid index across the whole query (0 if none)
    const unsigned short* __restrict__ p = part + (q * NSUB + lane) * SS;
    int firstval = (c > 0) ? (int)p[0] : 0;
    unsigned long long m = __ballot(c > 0);
    int first = 0;
    if (m) {
        int fl = __ffsll((unsigned long long)m) - 1;
        first = __shfl(firstval, fl);
    }

    int* __restrict__ o = idxg + q * SS;
    // parallel ordered copy (short, divergent tails are rare)
    for (int j = 0; j < c; ++j) {
        int s = off + j;
        if (s < SS) o[s] = (int)p[j];
    }
    // fill tail slots [total, 32) with first
    if (lane < SS && lane >= total) o[lane] = first;
}

// ---------------------------------------------------------------------------
// Kernel 5: grouping. One wave per query point; per-wave LDS tile [16][66]
// (no __syncthreads — tiles are wave-private, LDS pipe is in-order per wave;
// fences via s_waitcnt + memory clobber). Two 16-sample passes: gather 256B
// ft rows coalesced, transpose through LDS, write s-contiguous 64B segments.
// 16.9 KB LDS/block -> 8 blocks/CU = 32 waves/CU.
// ---------------------------------------------------------------------------
__global__ void __launch_bounds__(256) group_kernel(
    const float4* __restrict__ xyz4, const float* __restrict__ new_xyz,
    const float* __restrict__ ft, const int* __restrict__ idxg,
    float* __restrict__ out)
{
    __shared__ float tile[4][16 * 66];      // 4224 B per wave
    const int w    = threadIdx.x >> 6;
    const int lane = threadIdx.x & 63;
    const int q    = blockIdx.x * 4 + w;   // 0..8191
    const int b    = q >> 12;
    const int p    = q & (NP - 1);
    const int s    = lane & 31;

    const int idxv = idxg[q * SS + s];     // both half-waves read same 128B

    // --- grouped_xyz channels 0..2 ---
    float4 pt = xyz4[(b << 14) + idxv];
    float q0 = new_xyz[q * 3 + 0];
    float q1 = new_xyz[q * 3 + 1];
    float q2 = new_xyz[q * 3 + 2];
    if (lane < 32) {
        out[((b * NCH + 0) * NP + p) * SS + s] = pt.x - q0;
        out[((b * NCH + 1) * NP + p) * SS + s] = pt.y - q1;
        out[((b * NCH + 2) * NP + p) * SS + s] = pt.z - q2;
    }

    // --- feature channels, two passes of 16 samples ---
    float* tl = tile[w];
    const float* __restrict__ ftb = ft + (b << 14) * CC;
    const int sl = lane & 15;              // s within pass
    const int cq = lane >> 4;              // channel quarter 0..3
#pragma unroll
    for (int h = 0; h < 2; ++h) {
        // gather 16 rows of 256B (coalesced; 2x128B lines each)
#pragma unroll
        for (int s2 = 0; s2 < 16; ++s2) {
            int n = __shfl(idxv, h * 16 + s2);
            tl[s2 * 66 + lane] = ftb[(n << 6) + lane];
        }
        asm volatile("s_waitcnt lgkmcnt(0)" ::: "memory");  // writes visible wave-wide
        // write out[b][3+ch][p][h*16+sl]; banks (2*sl+cq) -> <=2-way, free
#pragma unroll
        for (int cp = 0; cp < 16; ++cp) {
            int ch = cp * 4 + cq;
            out[((b * NCH + 3 + ch) * NP + p) * SS + h * 16 + sl] = tl[sl * 66 + ch];
        }
        asm volatile("s_waitcnt lgkmcnt(0)" ::: "memory");  // reads drained before reuse
    }
}

// ---------------------------------------------------------------------------
extern "C" void kernel_launch(void* const* d_in, const int* in_sizes, int n_in,
                              void* d_out, int out_size, void* d_ws, size_t ws_size,
                              hipStream_t stream)
{
    const float* xyz      = (const float*)d_in[0];   // (B,N,3)
    const float* new_xyz  = (const float*)d_in[1];   // (B,NP,3)
    const float* features = (const float*)d_in[2];   // (B,C,N)
    float* out = (float*)d_out;                      // (B,67,NP,32)

    // workspace layout (bytes), total ~25.8 MB
    char* ws = (char*)d_ws;
    float4*         xyz4 = (float4*)(ws);                      // 524288 B
    float*          ft   = (float*)(ws + 524288);              // 8388608 B
    unsigned short* part = (unsigned short*)(ws + 8912896);    // 16777216 B
    unsigned char*  cntp = (unsigned char*)(ws + 25690112);    // 262144 B
    int*            idxg = (int*)(ws + 25952256);              // 1048576 B

    hipLaunchKernelGGL(pack_xyz_kernel, dim3((BB * NN) / 256), dim3(256), 0, stream,
                       xyz, xyz4);
    hipLaunchKernelGGL(transpose_feat_kernel, dim3(NN / 64, BB), dim3(256), 0, stream,
                       features, ft);
    // 8192 waves = 2048 blocks of 4 waves; wave id -> (batch, subset, query block)
    hipLaunchKernelGGL(query_kernel, dim3((BB * NSUB * (NP / QB)) / 4), dim3(256), 0, stream,
                       xyz4, new_xyz, part, cntp);
    hipLaunchKernelGGL(merge_kernel, dim3((BB * NP) / 4), dim3(256), 0, stream,
                       part, cntp, idxg);
    hipLaunchKernelGGL(group_kernel, dim3((BB * NP) / 4), dim3(256), 0, stream,
                       xyz4, new_xyz, ft, idxg, out);
}

// Round 10
// 146.109 us; speedup vs baseline: 2.1522x; 1.0002x over previous
//
#include <hip/hip_runtime.h>
#include <hip/hip_bf16.h>

// Problem constants (from reference setup_inputs)
#define BB 2
#define NN 16384          // points per batch (2^14)
#define NP 4096           // query points per batch
#define CC 64             // feature channels
#define SS 32             // nsample
#define NCH (3 + CC)      // 67 output channels

#define NSUB 32           // point-range subsets
#define SUBN (NN / NSUB)  // 512 points per subset
#define QB 32             // queries per wave in query_kernel

// ---------------------------------------------------------------------------
// Kernel 1: pack xyz (B,N,3) -> float4 (B,N,4) for 16B loads
// ---------------------------------------------------------------------------
__global__ void __launch_bounds__(256) pack_xyz_kernel(
    const float* __restrict__ xyz, float4* __restrict__ xyz4)
{
    int i = blockIdx.x * 256 + threadIdx.x;   // 0 .. B*N-1
    if (i < BB * NN) {
        float4 v;
        v.x = xyz[3 * i + 0];
        v.y = xyz[3 * i + 1];
        v.z = xyz[3 * i + 2];
        v.w = 0.0f;
        xyz4[i] = v;
    }
}

// ---------------------------------------------------------------------------
// Kernel 2: transpose features (B,C,N) -> (B,N,C) so per-sample channel
// gathers in the group kernel are 256B contiguous.
// ---------------------------------------------------------------------------
__global__ void __launch_bounds__(256) transpose_feat_kernel(
    const float* __restrict__ f, float* __restrict__ ft)
{
    __shared__ float tile[64 * 65];
    const int b  = blockIdx.y;
    const int n0 = blockIdx.x * 64;
    const int t  = threadIdx.x;
    const int tn  = t & 63;   // 0..63
    const int tc4 = t >> 6;   // 0..3
#pragma unroll
    for (int r = 0; r < 16; ++r) {
        int c = r * 4 + tc4;
        tile[c * 65 + tn] = f[((b * CC + c) << 14) + n0 + tn];  // coalesced read
    }
    __syncthreads();
#pragma unroll
    for (int r = 0; r < 16; ++r) {
        int nl = r * 4 + tc4;
        ft[((b << 14) + n0 + nl) * CC + tn] = tile[tn * 65 + nl];
    }
}

// ---------------------------------------------------------------------------
// Kernel 3: ball query partials — lane = POINT, queries broadcast as scalars.
// Each wave holds its subset's 512 points in registers (8 float4 per lane)
// and iterates QB=32 queries. Validity -> __ballot; matched lanes self-assign
// ordered slots via popcount(mask & lanemask_lt). Chunk order (k asc) x lane
// order (asc) = ascending point index, so per-subset lists stay ordered.
// Range test: for d2 >= 0, (bits(d2)-bits(lo)) < (bits(hi)-bits(lo)) is exact.
// ---------------------------------------------------------------------------
__global__ void __launch_bounds__(256) query_kernel(
    const float4* __restrict__ xyz4, const float* __restrict__ new_xyz,
    unsigned short* __restrict__ part, unsigned char* __restrict__ cntp)
{
#pragma clang fp contract(off)
    const int lane = threadIdx.x & 63;
    const int wid  = blockIdx.x * 4 + (threadIdx.x >> 6);  // 0..8191
    const int b    = wid >> 12;            // 4096 waves per batch
    const int r    = wid & 4095;
    const int sub  = r >> 7;               // 0..31
    const int qb   = r & 127;              // 0..127
    const int qbase = qb * QB;             // within-batch first query

    const float RMIN2 = (float)(0.4 * 0.4);
    const float RMAX2 = (float)(0.8 * 0.8);
    const unsigned ULO  = __float_as_uint(RMIN2);
    const unsigned URNG = __float_as_uint(RMAX2) - ULO;

    // load this wave's 512 points into registers: 8 chunks of 64 (coalesced)
    const float4* __restrict__ pb = xyz4 + (b << 14) + sub * SUBN;
    float4 P[8];
#pragma unroll
    for (int k = 0; k < 8; ++k) P[k] = pb[k * 64 + lane];

    const unsigned long long ltmask = (1ull << lane) - 1ull;
    int mycnt = 0;

    for (int j = 0; j < QB; ++j) {
        const int qg = b * NP + qbase + j;             // global query id
        // wave-uniform -> force scalar loads (s_load, scalar cache)
        const int qoff = __builtin_amdgcn_readfirstlane(qg * 3);
        const float qx = new_xyz[qoff + 0];
        const float qy = new_xyz[qoff + 1];
        const float qz = new_xyz[qoff + 2];

        unsigned short* __restrict__ mp = part + ((size_t)qg * NSUB + sub) * SS;
        int cnt = 0;
#pragma unroll
        for (int k = 0; k < 8; ++k) {
            float dx = P[k].x - qx;
            float dy = P[k].y - qy;
            float dz = P[k].z - qz;
            float dx2 = dx * dx;
            float dy2 = dy * dy;
            float dz2 = dz * dz;
            float d2 = (dx2 + dy2) + dz2;              // contract(off): JAX order
            bool valid = (__float_as_uint(d2) - ULO) < URNG;
            unsigned long long m = __ballot(valid);
            if (m) {                                   // wave-uniform, ~12% taken
                if (valid) {
                    int slot = cnt + (int)__popcll(m & ltmask);
                    if (slot < SS)
                        mp[slot] = (unsigned short)(sub * SUBN + k * 64 + lane);
                }
                cnt += (int)__popcll(m);
            }
        }
        if (cnt > SS) cnt = SS;
        mycnt = (lane == j) ? cnt : mycnt;             // collect for one store
    }
    if (lane < QB)
        cntp[(size_t)(b * NP + qbase + lane) * NSUB + sub] = (unsigned char)mycnt;
}

// ---------------------------------------------------------------------------
// Kernel 4 (FUSED merge+group). One wave per query.
// Merge phase: lane = subset (<32). Shfl prefix-sum of counts, scattered copy
// of ordered partials into per-wave LDS idx buffer, tail-fill with first
// valid index (0 if none). Then gather phase identical to previous rounds:
// 2 passes x 16 samples, 256B coalesced ft rows -> LDS [16][66] -> coalesced
// s-contiguous output writes. Wave-private LDS, fences via s_waitcnt only.
// LDS/block: 4*(16*66*4 + 32*4) = 17408 B -> 8 blocks/CU = 32 waves/CU.
// ---------------------------------------------------------------------------
__global__ void __launch_bounds__(256) group_kernel(
    const float4* __restrict__ xyz4, const float* __restrict__ new_xyz,
    const float* __restrict__ ft,
    const unsigned short* __restrict__ part, const unsigned char* __restrict__ cntp,
    float* __restrict__ out)
{
    __shared__ float tile[4][16 * 66];      // 4224 B per wave
    __shared__ int   idx_s[4][SS];          // 128 B per wave
    const int w    = threadIdx.x >> 6;
    const int lane = threadIdx.x & 63;
    const int q    = blockIdx.x * 4 + w;   // 0..8191
    const int b    = q >> 12;
    const int p    = q & (NP - 1);
    const int s    = lane & 31;

    // ---- merge phase (lane = subset for lanes < 32) ----
    int c = (lane < NSUB) ? (int)cntp[(size_t)q * NSUB + lane] : 0;

    int off = c;                            // inclusive prefix over lanes 0..31
#pragma unroll
    for (int d = 1; d < 32; d <<= 1) {
        int v = __shfl_up(off, d);
        if (lane >= d) off += v;
    }
    int total = __shfl(off, 31);
    if (total > SS) total = SS;
    off -= c;                               // exclusive prefix = output offset

    const unsigned short* __restrict__ pp = part + ((size_t)q * NSUB + (lane & 31)) * SS;
    int firstval = (c > 0) ? (int)pp[0] : 0;
    unsigned long long m = __ballot(c > 0);
    int first = 0;
    if (m) first = __shfl(firstval, __ffsll(m) - 1);

    for (int j = 0; j < c; ++j) {           // avg c ~ 1; ordered scatter to LDS
        int sl = off + j;
        if (sl < SS) idx_s[w][sl] = (int)pp[j];
    }
    if (lane >= total && lane < SS) idx_s[w][lane] = first;
    asm volatile("s_waitcnt lgkmcnt(0)" ::: "memory");  // idx_s visible wave-wide

    const int idxv = idx_s[w][s];           // final sample index (both halves)

    // ---- grouped_xyz channels 0..2 ----
    float4 pt = xyz4[(b << 14) + idxv];
    float q0 = new_xyz[q * 3 + 0];
    float q1 = new_xyz[q * 3 + 1];
    float q2 = new_xyz[q * 3 + 2];
    if (lane < 32) {
        out[((b * NCH + 0) * NP + p) * SS + s] = pt.x - q0;
        out[((b * NCH + 1) * NP + p) * SS + s] = pt.y - q1;
        out[((b * NCH + 2) * NP + p) * SS + s] = pt.z - q2;
    }

    // ---- feature channels, two passes of 16 samples ----
    float* tl = tile[w];
    const float* __restrict__ ftb = ft + (b << 14) * CC;
    const int sl = lane & 15;              // s within pass
    const int cq = lane >> 4;              // channel quarter 0..3
#pragma unroll
    for (int h = 0; h < 2; ++h) {
        // gather 16 rows of 256B (coalesced; 2x128B lines each)
#pragma unroll
        for (int s2 = 0; s2 < 16; ++s2) {
            int n = __shfl(idxv, h * 16 + s2);
            tl[s2 * 66 + lane] = ftb[(n << 6) + lane];
        }
        asm volatile("s_waitcnt lgkmcnt(0)" ::: "memory");  // writes visible wave-wide
        // write out[b][3+ch][p][h*16+sl]; banks (2*sl+cq) -> <=2-way, free
#pragma unroll
        for (int cp = 0; cp < 16; ++cp) {
            int ch = cp * 4 + cq;
            out[((b * NCH + 3 + ch) * NP + p) * SS + h * 16 + sl] = tl[sl * 66 + ch];
        }
        asm volatile("s_waitcnt lgkmcnt(0)" ::: "memory");  // reads drained before reuse
    }
}

// ---------------------------------------------------------------------------
extern "C" void kernel_launch(void* const* d_in, const int* in_sizes, int n_in,
                              void* d_out, int out_size, void* d_ws, size_t ws_size,
                              hipStream_t stream)
{
    const float* xyz      = (const float*)d_in[0];   // (B,N,3)
    const float* new_xyz  = (const float*)d_in[1];   // (B,NP,3)
    const float* features = (const float*)d_in[2];   // (B,C,N)
    float* out = (float*)d_out;                      // (B,67,NP,32)

    // workspace layout (bytes), total ~25 MB
    char* ws = (char*)d_ws;
    float4*         xyz4 = (float4*)(ws);                      // 524288 B
    float*          ft   = (float*)(ws + 524288);              // 8388608 B
    unsigned short* part = (unsigned short*)(ws + 8912896);    // 16777216 B
    unsigned char*  cntp = (unsigned char*)(ws + 25690112);    // 262144 B

    hipLaunchKernelGGL(pack_xyz_kernel, dim3((BB * NN) / 256), dim3(256), 0, stream,
                       xyz, xyz4);
    hipLaunchKernelGGL(transpose_feat_kernel, dim3(NN / 64, BB), dim3(256), 0, stream,
                       features, ft);
    // 8192 waves = 2048 blocks of 4 waves; wave id -> (batch, subset, query block)
    hipLaunchKernelGGL(query_kernel, dim3((BB * NSUB * (NP / QB)) / 4), dim3(256), 0, stream,
                       xyz4, new_xyz, part, cntp);
    hipLaunchKernelGGL(group_kernel, dim3((BB * NP) / 4), dim3(256), 0, stream,
                       xyz4, new_xyz, ft, part, cntp, out);
}

// Round 14
// 142.090 us; speedup vs baseline: 2.2131x; 1.0283x over previous
//
#include <hip/hip_runtime.h>
#include <hip/hip_bf16.h>

// Problem constants (from reference setup_inputs)
#define BB 2
#define NN 16384          // points per batch (2^14)
#define NP 4096           // query points per batch
#define CC 64             // feature channels
#define SS 32             // nsample
#define NCH (3 + CC)      // 67 output channels

#define NSUB 32           // point-range subsets
#define SUBN (NN / NSUB)  // 512 points per subset
#define QB 32             // queries per wave in query phase

#define TBLOCKS (BB * (NN / 64))            // 512 transpose blocks
#define QBLOCKS ((BB * NSUB * (NP / QB)) / 4) // 2048 query blocks

// ---------------------------------------------------------------------------
// Kernel 1 (heterogeneous): blocks [0,512) transpose features (B,C,N)->(B,N,C);
// blocks [512,2560) run the ball-query partials. The two halves share no data
// (query reads xyz directly), so co-dispatch is race-free and they overlap.
// ---------------------------------------------------------------------------
__global__ void __launch_bounds__(256) pre_kernel(
    const float* __restrict__ xyz, const float* __restrict__ new_xyz,
    const float* __restrict__ f, float* __restrict__ ft,
    unsigned short* __restrict__ part, unsigned char* __restrict__ cntp)
{
#pragma clang fp contract(off)
    __shared__ float tile[64 * 65];         // used by transpose branch only

    if (blockIdx.x < TBLOCKS) {
        // ---- transpose branch ----
        const int tb = blockIdx.x;
        const int b  = tb >> 8;             // 256 blocks per batch
        const int n0 = (tb & 255) << 6;
        const int t  = threadIdx.x;
        const int tn  = t & 63;             // 0..63
        const int tc4 = t >> 6;             // 0..3
#pragma unroll
        for (int r = 0; r < 16; ++r) {
            int c = r * 4 + tc4;
            tile[c * 65 + tn] = f[((b * CC + c) << 14) + n0 + tn];  // coalesced
        }
        __syncthreads();
#pragma unroll
        for (int r = 0; r < 16; ++r) {
            int nl = r * 4 + tc4;
            ft[((b << 14) + n0 + nl) * CC + tn] = tile[tn * 65 + nl];
        }
        return;
    }

    // ---- query branch: lane = POINT, queries broadcast as scalars ----
    const int lane = threadIdx.x & 63;
    const int wid  = (blockIdx.x - TBLOCKS) * 4 + (threadIdx.x >> 6); // 0..8191
    const int b    = wid >> 12;             // 4096 waves per batch
    const int r    = wid & 4095;
    const int sub  = r >> 7;                // 0..31
    const int qb   = r & 127;               // 0..127
    const int qbase = qb * QB;              // within-batch first query

    const float RMIN2 = (float)(0.4 * 0.4);
    const float RMAX2 = (float)(0.8 * 0.8);
    const unsigned ULO  = __float_as_uint(RMIN2);
    const unsigned URNG = __float_as_uint(RMAX2) - ULO;

    // load this wave's 512 points into registers straight from xyz (B,N,3):
    // 3 dword loads per chunk; 12B/lane stride -> L2-absorbed overfetch.
    const int pbase = (b << 14) + sub * SUBN;
    float px[8], py[8], pz[8];
#pragma unroll
    for (int k = 0; k < 8; ++k) {
        int a3 = (pbase + k * 64 + lane) * 3;
        px[k] = xyz[a3 + 0];
        py[k] = xyz[a3 + 1];
        pz[k] = xyz[a3 + 2];
    }

    const unsigned long long ltmask = (1ull << lane) - 1ull;
    int mycnt = 0;

    for (int j = 0; j < QB; ++j) {
        const int qg = b * NP + qbase + j;             // global query id
        // wave-uniform -> force scalar loads (s_load, scalar cache)
        const int qoff = __builtin_amdgcn_readfirstlane(qg * 3);
        const float qx = new_xyz[qoff + 0];
        const float qy = new_xyz[qoff + 1];
        const float qz = new_xyz[qoff + 2];

        unsigned short* __restrict__ mp = part + ((size_t)qg * NSUB + sub) * SS;
        int cnt = 0;
#pragma unroll
        for (int k = 0; k < 8; ++k) {
            float dx = px[k] - qx;
            float dy = py[k] - qy;
            float dz = pz[k] - qz;
            float dx2 = dx * dx;
            float dy2 = dy * dy;
            float dz2 = dz * dz;
            float d2 = (dx2 + dy2) + dz2;              // contract(off): JAX order
            bool valid = (__float_as_uint(d2) - ULO) < URNG;
            unsigned long long m = __ballot(valid);
            if (m) {                                   // wave-uniform, ~12% taken
                if (valid) {
                    int slot = cnt + (int)__popcll(m & ltmask);
                    if (slot < SS)
                        mp[slot] = (unsigned short)(sub * SUBN + k * 64 + lane);
                }
                cnt += (int)__popcll(m);
            }
        }
        if (cnt > SS) cnt = SS;
        mycnt = (lane == j) ? cnt : mycnt;             // collect for one store
    }
    if (lane < QB)
        cntp[(size_t)(b * NP + qbase + lane) * NSUB + sub] = (unsigned char)mycnt;
}

// ---------------------------------------------------------------------------
// Kernel 2 (FUSED merge+group). One wave per query.
// Merge phase: lane = subset (<32). Shfl prefix-sum of counts, scattered copy
// of ordered partials into per-wave LDS idx buffer, tail-fill with first
// valid index (0 if none). Gather phase: 2 passes x 16 samples, 256B
// coalesced ft rows -> LDS [16][66] -> coalesced s-contiguous output writes.
// Wave-private LDS, fences via s_waitcnt only.
// LDS/block: 4*(16*66*4 + 32*4) = 17408 B -> 8 blocks/CU = 32 waves/CU.
// ---------------------------------------------------------------------------
__global__ void __launch_bounds__(256) group_kernel(
    const float* __restrict__ xyz, const float* __restrict__ new_xyz,
    const float* __restrict__ ft,
    const unsigned short* __restrict__ part, const unsigned char* __restrict__ cntp,
    float* __restrict__ out)
{
    __shared__ float tile[4][16 * 66];      // 4224 B per wave
    __shared__ int   idx_s[4][SS];          // 128 B per wave
    const int w    = threadIdx.x >> 6;
    const int lane = threadIdx.x & 63;
    const int q    = blockIdx.x * 4 + w;   // 0..8191
    const int b    = q >> 12;
    const int p    = q & (NP - 1);
    const int s    = lane & 31;

    // ---- merge phase (lane = subset for lanes < 32) ----
    int c = (lane < NSUB) ? (int)cntp[(size_t)q * NSUB + lane] : 0;

    int off = c;                            // inclusive prefix over lanes 0..31
#pragma unroll
    for (int d = 1; d < 32; d <<= 1) {
        int v = __shfl_up(off, d);
        if (lane >= d) off += v;
    }
    int total = __shfl(off, 31);
    if (total > SS) total = SS;
    off -= c;                               // exclusive prefix = output offset

    const unsigned short* __restrict__ pp = part + ((size_t)q * NSUB + (lane & 31)) * SS;
    int firstval = (c > 0) ? (int)pp[0] : 0;
    unsigned long long m = __ballot(c > 0);
    int first = 0;
    if (m) first = __shfl(firstval, __ffsll(m) - 1);

    for (int j = 0; j < c; ++j) {           // avg c ~ 1; ordered scatter to LDS
        int sl = off + j;
        if (sl < SS) idx_s[w][sl] = (int)pp[j];
    }
    if (lane >= total && lane < SS) idx_s[w][lane] = first;
    asm volatile("s_waitcnt lgkmcnt(0)" ::: "memory");  // idx_s visible wave-wide

    const int idxv = idx_s[w][s];           // final sample index (both halves)

    // ---- grouped_xyz channels 0..2 (12B scattered reads from xyz) ----
    const int a3 = ((b << 14) + idxv) * 3;
    float ptx = xyz[a3 + 0];
    float pty = xyz[a3 + 1];
    float ptz = xyz[a3 + 2];
    float q0 = new_xyz[q * 3 + 0];
    float q1 = new_xyz[q * 3 + 1];
    float q2 = new_xyz[q * 3 + 2];
    if (lane < 32) {
        out[((b * NCH + 0) * NP + p) * SS + s] = ptx - q0;
        out[((b * NCH + 1) * NP + p) * SS + s] = pty - q1;
        out[((b * NCH + 2) * NP + p) * SS + s] = ptz - q2;
    }

    // ---- feature channels, two passes of 16 samples ----
    float* tl = tile[w];
    const float* __restrict__ ftb = ft + (size_t)(b << 14) * CC;
    const int sl = lane & 15;              // s within pass
    const int cq = lane >> 4;              // channel quarter 0..3
#pragma unroll
    for (int h = 0; h < 2; ++h) {
        // gather 16 rows of 256B (coalesced; 2x128B lines each)
#pragma unroll
        for (int s2 = 0; s2 < 16; ++s2) {
            int n = __shfl(idxv, h * 16 + s2);
            tl[s2 * 66 + lane] = ftb[(n << 6) + lane];
        }
        asm volatile("s_waitcnt lgkmcnt(0)" ::: "memory");  // writes visible wave-wide
        // write out[b][3+ch][p][h*16+sl]; banks (2*sl+cq) -> <=2-way, free
#pragma unroll
        for (int cp = 0; cp < 16; ++cp) {
            int ch = cp * 4 + cq;
            out[((b * NCH + 3 + ch) * NP + p) * SS + h * 16 + sl] = tl[sl * 66 + ch];
        }
        asm volatile("s_waitcnt lgkmcnt(0)" ::: "memory");  // reads drained before reuse
    }
}

// ---------------------------------------------------------------------------
extern "C" void kernel_launch(void* const* d_in, const int* in_sizes, int n_in,
                              void* d_out, int out_size, void* d_ws, size_t ws_size,
                              hipStream_t stream)
{
    const float* xyz      = (const float*)d_in[0];   // (B,N,3)
    const float* new_xyz  = (const float*)d_in[1];   // (B,NP,3)
    const float* features = (const float*)d_in[2];   // (B,C,N)
    float* out = (float*)d_out;                      // (B,67,NP,32)

    // workspace layout (bytes), total ~25.4 MB
    char* ws = (char*)d_ws;
    float*          ft   = (float*)(ws);                       // 8388608 B
    unsigned short* part = (unsigned short*)(ws + 8388608);    // 16777216 B
    unsigned char*  cntp = (unsigned char*)(ws + 25165824);    // 262144 B

    // heterogeneous: 512 transpose blocks + 2048 query blocks, overlapped
    hipLaunchKernelGGL(pre_kernel, dim3(TBLOCKS + QBLOCKS), dim3(256), 0, stream,
                       xyz, new_xyz, features, ft, part, cntp);
    hipLaunchKernelGGL(group_kernel, dim3((BB * NP) / 4), dim3(256), 0, stream,
                       xyz, new_xyz, ft, part, cntp, out);
}

// Round 18
// 140.480 us; speedup vs baseline: 2.2385x; 1.0115x over previous
//
#include <hip/hip_runtime.h>
#include <hip/hip_bf16.h>

// Problem constants (from reference setup_inputs)
#define BB 2
#define NN 16384          // points per batch (2^14)
#define NP 4096           // query points per batch
#define CC 64             // feature channels
#define SS 32             // nsample
#define NCH (3 + CC)      // 67 output channels

#define NSUB 32           // point-range subsets
#define SUBN (NN / NSUB)  // 512 points per subset
#define QB 32             // queries per wave in query phase

#define TBLOCKS (BB * (NN / 64))            // 512 transpose blocks
#define QBLOCKS ((BB * NSUB * (NP / QB)) / 4) // 2048 query blocks

// ---------------------------------------------------------------------------
// Kernel 1 (heterogeneous): blocks [0,512) transpose features (B,C,N)->(B,N,C);
// blocks [512,2560) run the ball-query partials. The two halves share no data
// (query reads xyz directly), so co-dispatch is race-free and they overlap.
// ---------------------------------------------------------------------------
__global__ void __launch_bounds__(256) pre_kernel(
    const float* __restrict__ xyz, const float* __restrict__ new_xyz,
    const float* __restrict__ f, float* __restrict__ ft,
    unsigned short* __restrict__ part, unsigned char* __restrict__ cntp)
{
#pragma clang fp contract(off)
    __shared__ float tile[64 * 65];         // used by transpose branch only

    if (blockIdx.x < TBLOCKS) {
        // ---- transpose branch ----
        const int tb = blockIdx.x;
        const int b  = tb >> 8;             // 256 blocks per batch
        const int n0 = (tb & 255) << 6;
        const int t  = threadIdx.x;
        const int tn  = t & 63;             // 0..63
        const int tc4 = t >> 6;             // 0..3
#pragma unroll
        for (int r = 0; r < 16; ++r) {
            int c = r * 4 + tc4;
            tile[c * 65 + tn] = f[((b * CC + c) << 14) + n0 + tn];  // coalesced
        }
        __syncthreads();
#pragma unroll
        for (int r = 0; r < 16; ++r) {
            int nl = r * 4 + tc4;
            ft[((b << 14) + n0 + nl) * CC + tn] = tile[tn * 65 + nl];
        }
        return;
    }

    // ---- query branch: lane = POINT, queries broadcast via v_readlane ----
    const int lane = threadIdx.x & 63;
    const int wid  = (blockIdx.x - TBLOCKS) * 4 + (threadIdx.x >> 6); // 0..8191
    const int b    = wid >> 12;             // 4096 waves per batch
    const int r    = wid & 4095;
    const int sub  = r >> 7;                // 0..31
    const int qb   = r & 127;               // 0..127
    const int qbase = qb * QB;              // within-batch first query

    const float RMIN2 = (float)(0.4 * 0.4);
    const float RMAX2 = (float)(0.8 * 0.8);
    const unsigned ULO  = __float_as_uint(RMIN2);
    const unsigned URNG = __float_as_uint(RMAX2) - ULO;

    // load this wave's 512 points into registers straight from xyz (B,N,3)
    const int pbase = (b << 14) + sub * SUBN;
    float px[8], py[8], pz[8];
#pragma unroll
    for (int k = 0; k < 8; ++k) {
        int a3 = (pbase + k * 64 + lane) * 3;
        px[k] = xyz[a3 + 0];
        py[k] = xyz[a3 + 1];
        pz[k] = xyz[a3 + 2];
    }

    // preload the 32 query coords: lane j (<32) holds query (qbase+j)'s x,y,z.
    // One-time 12B/lane scattered load; per-query broadcast is then a pure
    // register v_readlane (no s_load + lgkmcnt stall on the critical path).
    int qxi = 0, qyi = 0, qzi = 0;
    {
        int ql = (b * NP + qbase + (lane & 31)) * 3;
        qxi = __float_as_int(new_xyz[ql + 0]);
        qyi = __float_as_int(new_xyz[ql + 1]);
        qzi = __float_as_int(new_xyz[ql + 2]);
    }

    const unsigned long long ltmask = (1ull << lane) - 1ull;
    int mycnt = 0;

    for (int j = 0; j < QB; ++j) {
        const int qg = b * NP + qbase + j;             // global query id
        // wave-uniform broadcast from lane j's registers (readlane ignores exec)
        const float qx = __int_as_float(__builtin_amdgcn_readlane(qxi, j));
        const float qy = __int_as_float(__builtin_amdgcn_readlane(qyi, j));
        const float qz = __int_as_float(__builtin_amdgcn_readlane(qzi, j));

        unsigned short* __restrict__ mp = part + ((size_t)qg * NSUB + sub) * SS;
        int cnt = 0;
#pragma unroll
        for (int k = 0; k < 8; ++k) {
            float dx = px[k] - qx;
            float dy = py[k] - qy;
            float dz = pz[k] - qz;
            float dx2 = dx * dx;
            float dy2 = dy * dy;
            float dz2 = dz * dz;
            float d2 = (dx2 + dy2) + dz2;              // contract(off): JAX order
            bool valid = (__float_as_uint(d2) - ULO) < URNG;
            unsigned long long m = __ballot(valid);
            if (m) {                                   // wave-uniform, ~12% taken
                if (valid) {
                    int slot = cnt + (int)__popcll(m & ltmask);
                    if (slot < SS)
                        mp[slot] = (unsigned short)(sub * SUBN + k * 64 + lane);
                }
                cnt += (int)__popcll(m);
            }
        }
        if (cnt > SS) cnt = SS;
        mycnt = (lane == j) ? cnt : mycnt;             // collect for one store
    }
    if (lane < QB)
        cntp[(size_t)(b * NP + qbase + lane) * NSUB + sub] = (unsigned char)mycnt;
}

// ---------------------------------------------------------------------------
// Kernel 2 (FUSED merge+group). One wave per query.
// Merge phase: lane = subset (<32). Shfl prefix-sum of counts, scattered copy
// of ordered partials into per-wave LDS idx buffer, tail-fill with first
// valid index (0 if none). Gather phase: 2 passes x 16 samples, 256B
// coalesced ft rows -> LDS [16][66] -> coalesced s-contiguous output writes.
// Wave-private LDS, fences via s_waitcnt only.
// LDS/block: 4*(16*66*4 + 32*4) = 17408 B -> 8 blocks/CU = 32 waves/CU.
// ---------------------------------------------------------------------------
__global__ void __launch_bounds__(256) group_kernel(
    const float* __restrict__ xyz, const float* __restrict__ new_xyz,
    const float* __restrict__ ft,
    const unsigned short* __restrict__ part, const unsigned char* __restrict__ cntp,
    float* __restrict__ out)
{
    __shared__ float tile[4][16 * 66];      // 4224 B per wave
    __shared__ int   idx_s[4][SS];          // 128 B per wave
    const int w    = threadIdx.x >> 6;
    const int lane = threadIdx.x & 63;
    const int q    = blockIdx.x * 4 + w;   // 0..8191
    const int b    = q >> 12;
    const int p    = q & (NP - 1);
    const int s    = lane & 31;

    // ---- merge phase (lane = subset for lanes < 32) ----
    int c = (lane < NSUB) ? (int)cntp[(size_t)q * NSUB + lane] : 0;

    int off = c;                            // inclusive prefix over lanes 0..31
#pragma unroll
    for (int d = 1; d < 32; d <<= 1) {
        int v = __shfl_up(off, d);
        if (lane >= d) off += v;
    }
    int total = __shfl(off, 31);
    if (total > SS) total = SS;
    off -= c;                               // exclusive prefix = output offset

    const unsigned short* __restrict__ pp = part + ((size_t)q * NSUB + (lane & 31)) * SS;
    int firstval = (c > 0) ? (int)pp[0] : 0;
    unsigned long long m = __ballot(c > 0);
    int first = 0;
    if (m) first = __shfl(firstval, __ffsll(m) - 1);

    for (int j = 0; j < c; ++j) {           // avg c ~ 1; ordered scatter to LDS
        int sl = off + j;
        if (sl < SS) idx_s[w][sl] = (int)pp[j];
    }
    if (lane >= total && lane < SS) idx_s[w][lane] = first;
    asm volatile("s_waitcnt lgkmcnt(0)" ::: "memory");  // idx_s visible wave-wide

    const int idxv = idx_s[w][s];           // final sample index (both halves)

    // ---- grouped_xyz channels 0..2 (12B scattered reads from xyz) ----
    const int a3 = ((b << 14) + idxv) * 3;
    float ptx = xyz[a3 + 0];
    float pty = xyz[a3 + 1];
    float ptz = xyz[a3 + 2];
    float q0 = new_xyz[q * 3 + 0];
    float q1 = new_xyz[q * 3 + 1];
    float q2 = new_xyz[q * 3 + 2];
    if (lane < 32) {
        out[((b * NCH + 0) * NP + p) * SS + s] = ptx - q0;
        out[((b * NCH + 1) * NP + p) * SS + s] = pty - q1;
        out[((b * NCH + 2) * NP + p) * SS + s] = ptz - q2;
    }

    // ---- feature channels, two passes of 16 samples ----
    float* tl = tile[w];
    const float* __restrict__ ftb = ft + (size_t)(b << 14) * CC;
    const int sl = lane & 15;              // s within pass
    const int cq = lane >> 4;              // channel quarter 0..3
#pragma unroll
    for (int h = 0; h < 2; ++h) {
        // gather 16 rows of 256B (coalesced; 2x128B lines each)
#pragma unroll
        for (int s2 = 0; s2 < 16; ++s2) {
            int n = __shfl(idxv, h * 16 + s2);
            tl[s2 * 66 + lane] = ftb[(n << 6) + lane];
        }
        asm volatile("s_waitcnt lgkmcnt(0)" ::: "memory");  // writes visible wave-wide
        // write out[b][3+ch][p][h*16+sl]; banks (2*sl+cq) -> <=2-way, free
#pragma unroll
        for (int cp = 0; cp < 16; ++cp) {
            int ch = cp * 4 + cq;
            out[((b * NCH + 3 + ch) * NP + p) * SS + h * 16 + sl] = tl[sl * 66 + ch];
        }
        asm volatile("s_waitcnt lgkmcnt(0)" ::: "memory");  // reads drained before reuse
    }
}

// ---------------------------------------------------------------------------
extern "C" void kernel_launch(void* const* d_in, const int* in_sizes, int n_in,
                              void* d_out, int out_size, void* d_ws, size_t ws_size,
                              hipStream_t stream)
{
    const float* xyz      = (const float*)d_in[0];   // (B,N,3)
    const float* new_xyz  = (const float*)d_in[1];   // (B,NP,3)
    const float* features = (const float*)d_in[2];   // (B,C,N)
    float* out = (float*)d_out;                      // (B,67,NP,32)

    // workspace layout (bytes), total ~25.4 MB
    char* ws = (char*)d_ws;
    float*          ft   = (float*)(ws);                       // 8388608 B
    unsigned short* part = (unsigned short*)(ws + 8388608);    // 16777216 B
    unsigned char*  cntp = (unsigned char*)(ws + 25165824);    // 262144 B

    // heterogeneous: 512 transpose blocks + 2048 query blocks, overlapped
    hipLaunchKernelGGL(pre_kernel, dim3(TBLOCKS + QBLOCKS), dim3(256), 0, stream,
                       xyz, new_xyz, features, ft, part, cntp);
    hipLaunchKernelGGL(group_kernel, dim3((BB * NP) / 4), dim3(256), 0, stream,
                       xyz, new_xyz, ft, part, cntp, out);
}